// Round 10
// baseline (242.150 us; speedup 1.0000x reference)
//
#include <hip/hip_runtime.h>
#include <math.h>

#define LOG2E 1.44269504f

typedef unsigned short us;
typedef __attribute__((ext_vector_type(8))) short bf16x8;
typedef __attribute__((ext_vector_type(4))) float f32x4;
typedef __attribute__((ext_vector_type(16))) float f32x16;

static __device__ __forceinline__ us f2bf(float f) {  // RNE
  union { float f; unsigned u; } v; v.f = f;
  unsigned r = v.u + 0x7fffu + ((v.u >> 16) & 1u);
  return (us)(r >> 16);
}

// ---------------------------------------------------------------------------
// prep_kernel (R3 measured-best): blocks 0..2047 transpose x f32 -> xT bf16;
// blocks 2048..2495 weight repack.
// ---------------------------------------------------------------------------
__global__ __launch_bounds__(256) void prep_kernel(
    const float* __restrict__ x, const float* __restrict__ wq,
    const float* __restrict__ wk, const float* __restrict__ wv,
    us* __restrict__ xT, us* __restrict__ wqc, us* __restrict__ wkc,
    us* __restrict__ wvb) {
  __shared__ __align__(16) us lt[64 * 68];
  int bid = blockIdx.x;
  int tid = threadIdx.x;
  if (bid < 2048) {
    int b = bid >> 8, cb = (bid >> 6) & 3, nb = bid & 63;
    const float* xb = x + (((size_t)(b * 256 + cb * 64)) << 12);
    int nl = tid & 63, ch = tid >> 6;
#pragma unroll
    for (int p = 0; p < 16; p++) {
      int c = p * 4 + ch;
      lt[nl * 68 + c] = f2bf(xb[((size_t)c << 12) + (nb * 64 + nl)]);
    }
    __syncthreads();
    us* xTb = xT + (((size_t)b << 12) + nb * 64) * 256 + cb * 64;
    int cw = tid & 7, nr0 = tid >> 3;
#pragma unroll
    for (int p2 = 0; p2 < 2; p2++) {
      int nr = p2 * 32 + nr0;
      uint2 lo = *(const uint2*)&lt[nr * 68 + cw * 8];
      uint2 hi = *(const uint2*)&lt[nr * 68 + cw * 8 + 4];
      *(uint4*)&xTb[(size_t)nr * 256 + cw * 8] = make_uint4(lo.x, lo.y, hi.x, hi.y);
    }
  } else {
    int idx = (bid - 2048) * 256 + tid;
    if (idx < 24576) {
      int oc = idx / 768, r = idx % 768, t = r >> 8, ic = r & 255;
      wqc[idx] = f2bf(wq[(oc * 256 + ic) * 3 + t] * LOG2E);
    } else if (idx < 49152) {
      int j = idx - 24576;
      int oc = j / 768, r = j % 768, t = r >> 8, ic = r & 255;
      wkc[j] = f2bf(wk[(oc * 256 + ic) * 3 + t]);
    } else if (idx < 114688) {
      int j = idx - 49152;
      wvb[j] = f2bf(wv[j]);
    }
  }
}

// ---------------------------------------------------------------------------
// conv_kernel (R3 measured-best): blocks 0..511 q/k convs; 512..1023 v conv.
// ---------------------------------------------------------------------------
__global__ __launch_bounds__(256) void conv_kernel(
    const us* __restrict__ xT, const us* __restrict__ wqc,
    const us* __restrict__ wkc, const float* __restrict__ bq,
    const float* __restrict__ bk, const us* __restrict__ wvb,
    const float* __restrict__ bv, us* __restrict__ qT, us* __restrict__ kT,
    us* __restrict__ vblk) {
  int tid = threadIdx.x, lane = tid & 63, w = tid >> 6;
  int l15 = lane & 15, quad = lane >> 4;
  if (blockIdx.x < 512) {
    int bid = blockIdx.x;
    int b = bid & 7, rt = bid >> 3;
    int n0 = rt * 64, y = rt;
    bool isq = (w < 2);
    int m0 = (w & 1) * 16;
    const us* wc = isq ? wqc : wkc;
    const us* xTb = xT + (((size_t)b << 12) * 256);
    f32x4 acc[4];
#pragma unroll
    for (int nt = 0; nt < 4; nt++) acc[nt] = (f32x4){0.f, 0.f, 0.f, 0.f};
#pragma unroll
    for (int t = 0; t < 3; t++) {
      bool killT = (!isq) && ((t == 0 && y == 0) || (t == 2 && y == 63));
      if (!killT) {
        int dn = isq ? (t - 1) : (t - 1) * 64;
#pragma unroll
        for (int k8 = 0; k8 < 8; k8++) {
          int kloc = t * 256 + k8 * 32 + quad * 8;
          bf16x8 af = *(const bf16x8*)(wc + (size_t)(m0 + l15) * 768 + kloc);
          int ic = k8 * 32 + quad * 8;
#pragma unroll
          for (int nt = 0; nt < 4; nt++) {
            int nl = nt * 16 + l15;
            int ns = n0 + nl + dn;
            ns = ns < 0 ? 0 : (ns > 4095 ? 4095 : ns);
            bf16x8 bf = *(const bf16x8*)(xTb + (size_t)ns * 256 + ic);
            if (isq && ((t == 0 && nl == 0) || (t == 2 && nl == 63)))
              bf = (bf16x8){0, 0, 0, 0, 0, 0, 0, 0};
            acc[nt] = __builtin_amdgcn_mfma_f32_16x16x32_bf16(af, bf, acc[nt], 0, 0, 0);
          }
        }
      }
    }
    const float* bias = isq ? bq : bk;
    float bsc = isq ? LOG2E : 1.0f;
    us* outp = (isq ? qT : kT) + (((size_t)b << 12) * 32);
    float b0 = bias[m0 + quad * 4 + 0] * bsc;
    float b1 = bias[m0 + quad * 4 + 1] * bsc;
    float b2 = bias[m0 + quad * 4 + 2] * bsc;
    float b3 = bias[m0 + quad * 4 + 3] * bsc;
#pragma unroll
    for (int nt = 0; nt < 4; nt++) {
      int n = n0 + nt * 16 + l15;
      unsigned lo = (unsigned)f2bf(acc[nt][0] + b0) | ((unsigned)f2bf(acc[nt][1] + b1) << 16);
      unsigned hi = (unsigned)f2bf(acc[nt][2] + b2) | ((unsigned)f2bf(acc[nt][3] + b3) << 16);
      *(uint2*)(outp + (size_t)n * 32 + m0 + quad * 4) = make_uint2(lo, hi);
    }
  } else {
    int bid = blockIdx.x - 512;
    int b = bid & 7, nt0 = bid >> 3;
    int n0 = nt0 * 64;
    const us* xTb = xT + (((size_t)b << 12) * 256);
    f32x4 acc[4][4];  // [ct][nt]
#pragma unroll
    for (int ct = 0; ct < 4; ct++)
#pragma unroll
      for (int nt = 0; nt < 4; nt++) acc[ct][nt] = (f32x4){0.f, 0.f, 0.f, 0.f};
#pragma unroll
    for (int kk = 0; kk < 8; kk++) {
      bf16x8 bfr[4];
#pragma unroll
      for (int nt = 0; nt < 4; nt++)
        bfr[nt] = *(const bf16x8*)(xTb + (size_t)(n0 + nt * 16 + l15) * 256 + kk * 32 + quad * 8);
#pragma unroll
      for (int ct = 0; ct < 4; ct++) {
        bf16x8 af = *(const bf16x8*)(wvb + (size_t)(w * 64 + ct * 16 + l15) * 256 + kk * 32 + quad * 8);
#pragma unroll
        for (int nt = 0; nt < 4; nt++)
          acc[ct][nt] = __builtin_amdgcn_mfma_f32_16x16x32_bf16(af, bfr[nt], acc[ct][nt], 0, 0, 0);
      }
    }
    us* vb = vblk + ((size_t)b << 20);
#pragma unroll
    for (int ct = 0; ct < 4; ct++) {
#pragma unroll
      for (int r = 0; r < 4; r++) {
        int oc = w * 64 + ct * 16 + quad * 4 + r;
        float bvv = bv[oc];
#pragma unroll
        for (int nt = 0; nt < 4; nt++) {
          vb[((size_t)((n0 >> 4) + nt) * 256 + oc) * 16 + l15] = f2bf(acc[ct][nt][r] + bvv);
        }
      }
    }
  }
}

// ---------------------------------------------------------------------------
// Flash attention, (c64,i32) wave tiling: halves LDS P-read traffic (the
// ~45%-of-step pipe) by giving each wave a 32-row i-slice of P (4KB, 4x
// ds_read_b128, each feeding TWO mfma via the c-halves) and 64 channels of V
// (8KB from L2, prefetched a full iter ahead). MFMA count per wave-step
// unchanged (2 QK + 8 PV). QK role: jq=w&3 (16 j), ih=w>>2 (32 i, 2 mfma).
// PV role: cq=w&3 (64 c), ihp=w>>2 (32 i). R3's T15 ordering kept with a
// SINGLE V set via split prefetch: PREK(n+1); QKM(n); PVM(n-1) [consumes
// V(n-1) before overwrite]; PREV(n); SMW(n); BAR. 2-buffer P invariant as
// R3 (lgkmcnt(0)-only drain; prefetch stays in flight across barrier).
// grid 512 = 8b (XCD-stable) * 64 i-tiles; 2 blocks/CU.
// ---------------------------------------------------------------------------
__global__ __launch_bounds__(512, 4) void attn_kernel(
    const float* __restrict__ x, const us* __restrict__ qT,
    const us* __restrict__ kT, const us* __restrict__ vblk,
    const float* __restrict__ gamma_p, float* __restrict__ out) {
  __shared__ __align__(16) us pb[2][64 * 72];  // [i][j], stride 72
  __shared__ float lpart[4][64];

  int tid = threadIdx.x, lane = tid & 63, w = tid >> 6;
  int l15 = lane & 15, quad = lane >> 4;
  int l31 = lane & 31, h32 = lane >> 5;
  int jq = w & 3, ih = w >> 2;   // QK: j sixteenth, i half
  int cq = w & 3, ihp = w >> 2;  // PV: c quarter (64ch), i half

  int bid = blockIdx.x;
  int b = bid & 7, i0 = (bid >> 3) * 64;

  const us* qTb = qT + (((size_t)b << 12) * 32);
  const us* kTb = kT + (((size_t)b << 12) * 32);
  const us* vbb = vblk + ((size_t)b << 20);

  // q fragments: B-operand 16x16x32, i halves of this wave's 32 rows
  bf16x8 qfa = *(const bf16x8*)(qTb + (size_t)(i0 + ih * 32 + l15) * 32 + quad * 8);
  bf16x8 qfb = *(const bf16x8*)(qTb + (size_t)(i0 + ih * 32 + 16 + l15) * 32 + quad * 8);

  // invariant addresses (us units)
  const us* kbase = kTb + (size_t)(jq * 16 + l15) * 32 + quad * 8;   // +jt*2048
  const us* vbase = vbb + (size_t)(cq * 64 + l31) * 16 + h32 * 8;    // +jt*16384, +js*4096, +ch*512
  int pwi = (ih * 32 + l15) * 72 + jq * 16 + quad * 4;  // P write [i][j]; h=1: +1152
  int pri = (ihp * 32 + l31) * 72 + h32 * 8;            // P read; +js*16

  float lr0 = 0.f, lr1 = 0.f;
  f32x4 sa, sb;
  f32x16 o0, o1;  // ch=0 / ch=1 c-halves, i = i0 + ihp*32 + l31
#pragma unroll
  for (int rg = 0; rg < 16; rg++) { o0[rg] = 0.f; o1[rg] = 0.f; }

  bf16x8 kX, kY;                                   // K ping-pong
  bf16x8 va0, va1, va2, va3, vb0, vb1, vb2, vb3;   // V single set (ch0/ch1 x js)

#define PREK(N, KD)                                                            \
  do { KD = *(const bf16x8*)(kbase + (size_t)((N) & 63) * 2048); } while (0)

#define PREV(N)                                                                \
  do {                                                                         \
    const us* vp = vbase + (size_t)((N) & 63) * 16384;                         \
    va0 = *(const bf16x8*)(vp);                                                \
    vb0 = *(const bf16x8*)(vp + 512);                                          \
    va1 = *(const bf16x8*)(vp + 4096);                                         \
    vb1 = *(const bf16x8*)(vp + 4608);                                         \
    va2 = *(const bf16x8*)(vp + 8192);                                         \
    vb2 = *(const bf16x8*)(vp + 8704);                                         \
    va3 = *(const bf16x8*)(vp + 12288);                                        \
    vb3 = *(const bf16x8*)(vp + 12800);                                        \
  } while (0)

#define QKM(KC)                                                                \
  do {                                                                         \
    __builtin_amdgcn_s_setprio(1);                                             \
    sa = __builtin_amdgcn_mfma_f32_16x16x32_bf16(KC, qfa, (f32x4){0.f, 0.f, 0.f, 0.f}, 0, 0, 0); \
    sb = __builtin_amdgcn_mfma_f32_16x16x32_bf16(KC, qfb, (f32x4){0.f, 0.f, 0.f, 0.f}, 0, 0, 0); \
    __builtin_amdgcn_s_setprio(0);                                             \
  } while (0)

#define PVM(BUF)                                                               \
  do {                                                                         \
    const us* pr = (const us*)pb + (BUF) * 4608 + pri;                         \
    __builtin_amdgcn_s_setprio(1);                                             \
    bf16x8 pf;                                                                 \
    pf = *(const bf16x8*)(pr + 0);                                             \
    o0 = __builtin_amdgcn_mfma_f32_32x32x16_bf16(va0, pf, o0, 0, 0, 0);        \
    o1 = __builtin_amdgcn_mfma_f32_32x32x16_bf16(vb0, pf, o1, 0, 0, 0);        \
    pf = *(const bf16x8*)(pr + 16);                                            \
    o0 = __builtin_amdgcn_mfma_f32_32x32x16_bf16(va1, pf, o0, 0, 0, 0);        \
    o1 = __builtin_amdgcn_mfma_f32_32x32x16_bf16(vb1, pf, o1, 0, 0, 0);        \
    pf = *(const bf16x8*)(pr + 32);                                            \
    o0 = __builtin_amdgcn_mfma_f32_32x32x16_bf16(va2, pf, o0, 0, 0, 0);        \
    o1 = __builtin_amdgcn_mfma_f32_32x32x16_bf16(vb2, pf, o1, 0, 0, 0);        \
    pf = *(const bf16x8*)(pr + 48);                                            \
    o0 = __builtin_amdgcn_mfma_f32_32x32x16_bf16(va3, pf, o0, 0, 0, 0);        \
    o1 = __builtin_amdgcn_mfma_f32_32x32x16_bf16(vb3, pf, o1, 0, 0, 0);        \
    __builtin_amdgcn_s_setprio(0);                                             \
  } while (0)

#define SMW(BUF)                                                               \
  do {                                                                         \
    us* pw = (us*)pb + (BUF) * 4608 + pwi;                                     \
    {                                                                          \
      float p0 = __builtin_amdgcn_exp2f(sa[0]);                                \
      float p1 = __builtin_amdgcn_exp2f(sa[1]);                                \
      float p2 = __builtin_amdgcn_exp2f(sa[2]);                                \
      float p3 = __builtin_amdgcn_exp2f(sa[3]);                                \
      lr0 += (p0 + p1) + (p2 + p3);                                            \
      unsigned e0, e1;                                                         \
      asm("v_cvt_pk_bf16_f32 %0, %1, %2" : "=v"(e0) : "v"(p0), "v"(p1));       \
      asm("v_cvt_pk_bf16_f32 %0, %1, %2" : "=v"(e1) : "v"(p2), "v"(p3));       \
      *(uint2*)pw = make_uint2(e0, e1);                                        \
    }                                                                          \
    {                                                                          \
      float p0 = __builtin_amdgcn_exp2f(sb[0]);                                \
      float p1 = __builtin_amdgcn_exp2f(sb[1]);                                \
      float p2 = __builtin_amdgcn_exp2f(sb[2]);                                \
      float p3 = __builtin_amdgcn_exp2f(sb[3]);                                \
      lr1 += (p0 + p1) + (p2 + p3);                                            \
      unsigned e0, e1;                                                         \
      asm("v_cvt_pk_bf16_f32 %0, %1, %2" : "=v"(e0) : "v"(p0), "v"(p1));       \
      asm("v_cvt_pk_bf16_f32 %0, %1, %2" : "=v"(e1) : "v"(p2), "v"(p3));       \
      *(uint2*)(pw + 1152) = make_uint2(e0, e1);                               \
    }                                                                          \
  } while (0)

#define BAR                                                                    \
  do {                                                                         \
    asm volatile("s_waitcnt lgkmcnt(0)" ::: "memory");                         \
    __builtin_amdgcn_s_barrier();                                              \
    __builtin_amdgcn_sched_barrier(0);                                         \
  } while (0)

  PREK(0, kX);
  // iter 0 (no PV)
  PREK(1, kY);
  QKM(kX);
  PREV(0);
  SMW(0);
  BAR;
  // iter 1
  PREK(2, kX);
  QKM(kY);
  PVM(0);
  PREV(1);
  SMW(1);
  BAR;
  for (int jt2 = 1; jt2 < 32; jt2++) {
    PREK(2 * jt2 + 1, kY);
    QKM(kX);
    PVM(1);
    PREV(2 * jt2);
    SMW(0);
    BAR;
    PREK(2 * jt2 + 2, kX);
    QKM(kY);
    PVM(0);
    PREV(2 * jt2 + 1);
    SMW(1);
    BAR;
  }
  // epilogue: PV(63) — buf 63&1 = 1, V(63) resident
  PVM(1);

#undef PREK
#undef PREV
#undef QKM
#undef PVM
#undef SMW
#undef BAR

  // ---- final l: lane holds partials for i = ih*32 + (h?16:0) + l15 over
  //      j = jq*16 + quad*4 + r; quad-sum via shfl (same l15 => same i),
  //      then combine the 4 jq sixteenths via LDS ----
  float t0 = lr0, t1 = lr1;
  t0 += __shfl_xor(t0, 16);
  t0 += __shfl_xor(t0, 32);
  t1 += __shfl_xor(t1, 16);
  t1 += __shfl_xor(t1, 32);
  if (quad == 0) {
    lpart[jq][ih * 32 + l15] = t0;
    lpart[jq][ih * 32 + 16 + l15] = t1;
  }
  __syncthreads();
  float g = gamma_p[0];
  const float* xb = x + ((size_t)b << 20);
  float* ob = out + ((size_t)b << 20);
  int il = ihp * 32 + l31;
  float gl = g / (lpart[0][il] + lpart[1][il] + lpart[2][il] + lpart[3][il]);
  int i = i0 + il;
#pragma unroll
  for (int ch = 0; ch < 2; ch++) {
    const f32x16& o = (ch == 0) ? o0 : o1;
#pragma unroll
    for (int rg = 0; rg < 16; rg++) {
      int c = cq * 64 + ch * 32 + ((rg & 3) + 8 * (rg >> 2) + 4 * h32);
      size_t idx = ((size_t)c << 12) + i;
      ob[idx] = o[rg] * gl + xb[idx];
    }
  }
}

// ---------------------------------------------------------------------------
extern "C" void kernel_launch(void* const* d_in, const int* in_sizes, int n_in,
                              void* d_out, int out_size, void* d_ws, size_t ws_size,
                              hipStream_t stream) {
  const float* x = (const float*)d_in[0];
  const float* wq = (const float*)d_in[1];
  const float* bq = (const float*)d_in[2];
  const float* wk = (const float*)d_in[3];
  const float* bk = (const float*)d_in[4];
  const float* wv = (const float*)d_in[5];
  const float* bv = (const float*)d_in[6];
  const float* gamma = (const float*)d_in[7];
  float* out = (float*)d_out;

  us* xT = (us*)d_ws;                 // 8,388,608
  us* qT = xT + (size_t)8388608;      // 1,048,576
  us* kT = qT + (size_t)1048576;      // 1,048,576
  us* vblk = kT + (size_t)1048576;    // 8,388,608
  us* wqc = vblk + (size_t)8388608;   // 24,576
  us* wkc = wqc + (size_t)24576;      // 24,576
  us* wvb = wkc + (size_t)24576;      // 65,536

  prep_kernel<<<2496, 256, 0, stream>>>(x, wq, wk, wv, xT, wqc, wkc, wvb);
  conv_kernel<<<1024, 256, 0, stream>>>(xT, wqc, wkc, bq, bk, wvb, bv, qT, kT, vblk);
  attn_kernel<<<512, 512, 0, stream>>>(x, qT, kT, vblk, gamma, out);
}